// Round 4
// baseline (281.409 us; speedup 1.0000x reference)
//
#include <hip/hip_runtime.h>
#include <hip/hip_bf16.h>
#include <stdint.h>

// DenseGraphAttentionHead N=8192, IN=512, OUT=256, ~50% dense int32 mask.
//
// Pipeline:
//   k_convert_w : W f32 -> bf16 chunked (16B chunk (kb,row) at kb*2048+row*8).
//   k_wh        : Wh = nodes@W^T + b (mfma 16x16x32 bf16) -> WhL chunked bf16
//                 (chunk (jb,n) at jb*2048+n*8), s1/s2 f32 from f32 acc.
//   k_mask      : int32 mask (268 MB, the irreducible HBM stream) -> bitmask
//                 bm[row][wj] (8.4 MB) via __ballot. Pure streaming kernel.
//   k_attn      : fused masked-softmax @ Wh on the BITMASK. Grid = 64
//                 row-tiles(BM=128) x 4 j-chunks(2048); block = 8 waves =
//                 4 rowgroups(32 rows) x 2 j-subchunks(1024). js=1 waves
//                 merge into js=0 waves via LDS (2 phases, XOR-swizzled);
//                 js=0 waves write f32 partials pnum[jc]/pden[jc].
//   k_comb      : out = sum_jc(pnum) / sum_jc(pden).
//
// MFMA conventions (verified R1/R2 on this problem):
//   A frag: lane&15 = m, k = (lane>>4)*8 + i ; B same per-lane k order
//   D: col = lane&15, row = (lane>>4)*4 + reg

#define NN 8192
#define IND 512
#define OUTD 256

typedef __attribute__((ext_vector_type(8))) short short8;
typedef __attribute__((ext_vector_type(4))) short short4v;
typedef __attribute__((ext_vector_type(4))) float f32x4;

static __device__ __forceinline__ short f2bf(float f) {
  return __builtin_bit_cast(short, __float2bfloat16(f));
}

extern "C" __global__ __launch_bounds__(256) void k_convert_w(
    const float* __restrict__ W, short* __restrict__ W2) {
  const int t = blockIdx.x * 256 + threadIdx.x;  // 16384 threads
  const int row = t >> 6, kb = t & 63;
  const float* src = W + row * IND + kb * 8;
  f32x4 x0 = *(const f32x4*)src;
  f32x4 x1 = *(const f32x4*)(src + 4);
  short8 o;
  o[0] = f2bf(x0[0]); o[1] = f2bf(x0[1]); o[2] = f2bf(x0[2]); o[3] = f2bf(x0[3]);
  o[4] = f2bf(x1[0]); o[5] = f2bf(x1[1]); o[6] = f2bf(x1[2]); o[7] = f2bf(x1[3]);
  *(short8*)(W2 + (size_t)kb * 2048 + row * 8) = o;
}

extern "C" __global__ __launch_bounds__(128) void k_wh(
    const float* __restrict__ nodes, const short* __restrict__ W2,
    const float* __restrict__ Wb, const float* __restrict__ a1w,
    const float* __restrict__ a1b, const float* __restrict__ a2w,
    const float* __restrict__ a2b, short* __restrict__ WhL,
    float* __restrict__ s1, float* __restrict__ s2) {
  const int tid = threadIdx.x;
  const int wv = tid >> 6, lane = tid & 63, g = lane >> 4, m = lane & 15;
  const int rowbase = blockIdx.x * 32 + wv * 16;

  f32x4 acc[16];
#pragma unroll
  for (int nf = 0; nf < 16; ++nf) acc[nf] = (f32x4){0.f, 0.f, 0.f, 0.f};

  const float* arow = nodes + (size_t)(rowbase + m) * IND;
  const short* bb = W2 + (size_t)g * 2048 + m * 8;
#pragma unroll 4
  for (int k0 = 0; k0 < IND; k0 += 32) {
    const float* ap = arow + k0 + g * 8;
    f32x4 x0 = *(const f32x4*)ap;
    f32x4 x1 = *(const f32x4*)(ap + 4);
    short8 af;
    af[0] = f2bf(x0[0]); af[1] = f2bf(x0[1]); af[2] = f2bf(x0[2]); af[3] = f2bf(x0[3]);
    af[4] = f2bf(x1[0]); af[5] = f2bf(x1[1]); af[6] = f2bf(x1[2]); af[7] = f2bf(x1[3]);
    const short* bk = bb + (size_t)(k0 >> 3) * 2048;
#pragma unroll
    for (int nf = 0; nf < 16; ++nf) {
      short8 bf = *(const short8*)(bk + nf * 128);
      acc[nf] = __builtin_amdgcn_mfma_f32_16x16x32_bf16(af, bf, acc[nf], 0, 0, 0);
    }
  }

  float p1[4] = {0.f, 0.f, 0.f, 0.f}, p2[4] = {0.f, 0.f, 0.f, 0.f};
#pragma unroll
  for (int nf = 0; nf < 16; ++nf) {
    const int n = nf * 16 + m;
    const float b = Wb[n], c1 = a1w[n], c2 = a2w[n];
#pragma unroll
    for (int r = 0; r < 4; ++r) {
      float v = acc[nf][r] + b;
      acc[nf][r] = v;
      p1[r] += c1 * v;
      p2[r] += c2 * v;
    }
  }
#pragma unroll
  for (int off = 1; off < 16; off <<= 1) {
#pragma unroll
    for (int r = 0; r < 4; ++r) {
      p1[r] += __shfl_xor(p1[r], off);
      p2[r] += __shfl_xor(p2[r], off);
    }
  }
  if (m == 0) {
    const float b1 = a1b[0], b2 = a2b[0];
#pragma unroll
    for (int r = 0; r < 4; ++r) {
      const int row = rowbase + g * 4 + r;
      s1[row] = p1[r] + b1;
      s2[row] = p2[r] + b2;
    }
  }

  const size_t cbase = ((size_t)(rowbase >> 3) + (g >> 1)) * 2048 + (g & 1) * 4;
#pragma unroll
  for (int nf = 0; nf < 16; ++nf) {
    short4v o;
#pragma unroll
    for (int r = 0; r < 4; ++r) o[r] = f2bf(acc[nf][r]);
    *(short4v*)(WhL + cbase + (size_t)(nf * 16 + m) * 8) = o;
  }
}

// int32 mask -> bitmask. bm[row*256 + wj] bit b = mask[row][wj*32+b] != 0.
extern "C" __global__ __launch_bounds__(256) void k_mask(
    const int* __restrict__ mask, uint32_t* __restrict__ bm) {
  const int tid = threadIdx.x;
  const int wv = tid >> 6, lane = tid & 63;
  const int gw = blockIdx.x * 4 + wv;           // 4096 waves
  const size_t base = (size_t)gw * 16384;       // 64 iters x 256 ints
#pragma unroll 4
  for (int it = 0; it < 64; ++it) {
    const size_t ib = base + (size_t)it * 256;
    unsigned long long b0 = __ballot(mask[ib + lane] != 0);
    unsigned long long b1 = __ballot(mask[ib + 64 + lane] != 0);
    unsigned long long b2 = __ballot(mask[ib + 128 + lane] != 0);
    unsigned long long b3 = __ballot(mask[ib + 192 + lane] != 0);
    if (lane < 8) {
      unsigned long long s01 = (lane & 2) ? b1 : b0;
      unsigned long long s23 = (lane & 2) ? b3 : b2;
      unsigned long long sel = (lane & 4) ? s23 : s01;
      bm[ib / 32 + lane] = (uint32_t)(sel >> ((lane & 1) * 32));
    }
  }
}

extern "C" __global__ __launch_bounds__(512, 2) void k_attn(
    const uint32_t* __restrict__ bm, const short* __restrict__ WhL,
    const float* __restrict__ s1, const float* __restrict__ s2,
    float* __restrict__ pnum, float* __restrict__ pden) {
  __shared__ f32x4 cbuf[4][64][16];   // 64 KiB, js-combine buffer
  __shared__ float dbuf[4][2][16];    // den halves from js=1 waves

  const int tid = threadIdx.x;
  const int w = tid >> 6, lane = tid & 63, g = lane >> 4, m = lane & 15;
  const int rt = blockIdx.x >> 2, jc = blockIdx.x & 3;
  const int rg = w >> 1, js = w & 1;
  const int rowbase = rt * 128 + rg * 32;
  const int jbase = jc * 2048 + js * 1024;

  const float s1a = s1[rowbase + m];
  const float s1b = s1[rowbase + 16 + m];

  f32x4 acc0[16], acc1[16];
#pragma unroll
  for (int nf = 0; nf < 16; ++nf) {
    acc0[nf] = (f32x4){0.f, 0.f, 0.f, 0.f};
    acc1[nf] = (f32x4){0.f, 0.f, 0.f, 0.f};
  }
  float den0 = 0.f, den1 = 0.f;

  const uint32_t* bw0 = bm + (size_t)(rowbase + m) * 256 + (jbase >> 5);
  const uint32_t* bw1 = bw0 + (size_t)16 * 256;
  const float* sp = s2 + jbase + g * 8;
  const short* bb = WhL + ((size_t)(jbase >> 3) + g) * 2048 + (size_t)m * 8;

  uint32_t cw0 = bw0[0], cw1 = bw1[0];
  f32x4 cs0 = *(const f32x4*)sp;
  f32x4 cs1 = *(const f32x4*)(sp + 4);

  auto build = [&](float s1h, uint32_t bits, const f32x4& slo, const f32x4& shi,
                   float& den) -> short8 {
    short8 af;
#pragma unroll
    for (int i = 0; i < 8; ++i) {
      float sv = s1h + (i < 4 ? slo[i] : shi[i - 4]);
      sv = fmaxf(sv, 0.2f * sv);  // leaky-relu
      float pv = (bits & (1u << i)) ? __expf(sv) : 0.f;
      den += pv;
      af[i] = f2bf(pv);
    }
    return af;
  };

#pragma unroll 2
  for (int u = 0; u < 32; ++u) {
    const int un = (u < 31) ? (u + 1) : 31;
    uint32_t nw0 = bw0[un], nw1 = bw1[un];
    f32x4 ns0 = *(const f32x4*)(sp + un * 32);
    f32x4 ns1 = *(const f32x4*)(sp + un * 32 + 4);

    short8 af0 = build(s1a, cw0 >> (g * 8), cs0, cs1, den0);
    short8 af1 = build(s1b, cw1 >> (g * 8), cs0, cs1, den1);

    const short* bu = bb + (size_t)u * 8192;
#pragma unroll
    for (int nf = 0; nf < 16; ++nf) {
      short8 bf = *(const short8*)(bu + nf * 128);
      acc0[nf] = __builtin_amdgcn_mfma_f32_16x16x32_bf16(af0, bf, acc0[nf], 0, 0, 0);
      acc1[nf] = __builtin_amdgcn_mfma_f32_16x16x32_bf16(af1, bf, acc1[nf], 0, 0, 0);
    }
    cw0 = nw0; cw1 = nw1; cs0 = ns0; cs1 = ns1;
  }

  // per-wave den reduction: every lane ends holding den for row (lane&15)
  den0 += __shfl_xor(den0, 16); den0 += __shfl_xor(den0, 32);
  den1 += __shfl_xor(den1, 16); den1 += __shfl_xor(den1, 32);

  // js-combine: odd waves (js=1) hand acc/den to even waves (js=0)
  __syncthreads();
  if (js) {
#pragma unroll
    for (int nf = 0; nf < 16; ++nf) cbuf[rg][lane][nf ^ (lane & 7)] = acc0[nf];
    if (lane < 16) { dbuf[rg][0][m] = den0; dbuf[rg][1][m] = den1; }
  }
  __syncthreads();
  if (!js) {
#pragma unroll
    for (int nf = 0; nf < 16; ++nf) acc0[nf] += cbuf[rg][lane][nf ^ (lane & 7)];
    den0 += dbuf[rg][0][m];
    den1 += dbuf[rg][1][m];
  }
  __syncthreads();
  if (js) {
#pragma unroll
    for (int nf = 0; nf < 16; ++nf) cbuf[rg][lane][nf ^ (lane & 7)] = acc1[nf];
  }
  __syncthreads();
  if (js) return;

#pragma unroll
  for (int nf = 0; nf < 16; ++nf) acc1[nf] += cbuf[rg][lane][nf ^ (lane & 7)];

  if (lane < 16) {
    pden[jc * NN + rowbase + m] = den0;
    pden[jc * NN + rowbase + 16 + m] = den1;
  }

  float* pn = pnum + (size_t)jc * NN * OUTD;
#pragma unroll
  for (int r = 0; r < 4; ++r) {
    const int q = g * 4 + r;
    const size_t r0 = (size_t)(rowbase + q) * OUTD;
    const size_t r1 = (size_t)(rowbase + 16 + q) * OUTD;
#pragma unroll
    for (int nf = 0; nf < 16; ++nf) {
      pn[r0 + nf * 16 + m] = acc0[nf][r];
      pn[r1 + nf * 16 + m] = acc1[nf][r];
    }
  }
}

extern "C" __global__ __launch_bounds__(256) void k_comb(
    const float* __restrict__ pnum, const float* __restrict__ pden,
    float* __restrict__ out) {
  const int idx = blockIdx.x * 256 + threadIdx.x;  // 524288 threads
  const int row = idx >> 6, c4 = (idx & 63) * 4;
  f32x4 s = (f32x4){0.f, 0.f, 0.f, 0.f};
  float d = 0.f;
#pragma unroll
  for (int jc = 0; jc < 4; ++jc) {
    f32x4 v = *(const f32x4*)(pnum + ((size_t)jc * NN + row) * OUTD + c4);
    s += v;
    d += pden[jc * NN + row];
  }
  const float inv = 1.f / d;
  *(f32x4*)(out + (size_t)row * OUTD + c4) = s * inv;
}

extern "C" void kernel_launch(void* const* d_in, const int* in_sizes, int n_in,
                              void* d_out, int out_size, void* d_ws, size_t ws_size,
                              hipStream_t stream) {
  const float* nodes = (const float*)d_in[0];
  const int*   mask  = (const int*)d_in[1];
  const float* W_w   = (const float*)d_in[2];
  const float* W_b   = (const float*)d_in[3];
  const float* a1w   = (const float*)d_in[4];
  const float* a1b   = (const float*)d_in[5];
  const float* a2w   = (const float*)d_in[6];
  const float* a2b   = (const float*)d_in[7];
  float* out = (float*)d_out;

  char* ws = (char*)d_ws;
  short*    WhL  = (short*)(ws);                                  // 4 MiB
  float*    s1   = (float*)(ws + (size_t)4  * 1024 * 1024);       // 32 KiB
  float*    s2   = (float*)(ws + (size_t)4  * 1024 * 1024 + 32768);
  short*    W2   = (short*)(ws + (size_t)4  * 1024 * 1024 + 65536); // 256 KiB
  uint32_t* bmp  = (uint32_t*)(ws + (size_t)5  * 1024 * 1024);    // 8 MiB
  float*    pnum = (float*)(ws + (size_t)16 * 1024 * 1024);       // 32 MiB
  float*    pden = (float*)(ws + (size_t)48 * 1024 * 1024);       // 128 KiB

  hipLaunchKernelGGL(k_convert_w, dim3(64), dim3(256), 0, stream, W_w, W2);
  hipLaunchKernelGGL(k_wh, dim3(256), dim3(128), 0, stream,
                     nodes, W2, W_b, a1w, a1b, a2w, a2b, WhL, s1, s2);
  hipLaunchKernelGGL(k_mask, dim3(1024), dim3(256), 0, stream, mask, bmp);
  hipLaunchKernelGGL(k_attn, dim3(256), dim3(512), 0, stream,
                     bmp, WhL, s1, s2, pnum, pden);
  hipLaunchKernelGGL(k_comb, dim3(2048), dim3(256), 0, stream,
                     pnum, pden, out);
}